// Round 1
// baseline (401.104 us; speedup 1.0000x reference)
//
#include <hip/hip_runtime.h>

#define B 8
#define C 256
#define HW 18432          // 96*192
#define K 19
#define EPS_MEAN 1e-6f
#define EPS_COS 1e-8f
#define PAD 257           // LDS stride: bank = (k+c)%32, conflict-free across k

// ---------------- per-(b,k) pixel counts ----------------
__global__ __launch_bounds__(256) void k_counts(const int* __restrict__ target,
                                                int* __restrict__ counts) {
    __shared__ int hist[K * 256];
    __shared__ int red[K][4];
    const int tid = threadIdx.x, b = blockIdx.x;
    for (int k = 0; k < K; ++k) hist[k * 256 + tid] = 0;
    const int4* t4 = (const int4*)(target + b * HW);
    for (int i = 0; i < HW / 1024; ++i) {
        int4 t = t4[i * 256 + tid];
        if ((unsigned)t.x < K) hist[t.x * 256 + tid]++;
        if ((unsigned)t.y < K) hist[t.y * 256 + tid]++;
        if ((unsigned)t.z < K) hist[t.z * 256 + tid]++;
        if ((unsigned)t.w < K) hist[t.w * 256 + tid]++;
    }
    __syncthreads();
    const int wid = tid >> 6, lane = tid & 63;
    for (int k = 0; k < K; ++k) {
        int v = hist[k * 256 + tid];
        for (int off = 32; off; off >>= 1) v += __shfl_xor(v, off);
        if (lane == 0) red[k][wid] = v;
    }
    __syncthreads();
    if (tid < K) counts[b * K + tid] = red[tid][0] + red[tid][1] + red[tid][2] + red[tid][3];
}

// ---------------- per-(z,b,c) class sums (block owns one channel plane) ----------------
__global__ __launch_bounds__(256) void k_sums(const float* __restrict__ fS,
                                              const float* __restrict__ fT,
                                              const int* __restrict__ target,
                                              float* __restrict__ sums) {
    __shared__ float hist[K * 256];
    __shared__ float red[K][4];
    const int tid = threadIdx.x;
    const int c = blockIdx.x, b = blockIdx.y, z = blockIdx.z;
    const float* feat = z ? fT : fS;
    for (int k = 0; k < K; ++k) hist[k * 256 + tid] = 0.0f;
    const float4* f4 = (const float4*)(feat + (size_t)(b * C + c) * HW);
    const int4*   t4 = (const int4*)(target + b * HW);
    for (int i = 0; i < HW / 1024; ++i) {
        float4 v = f4[i * 256 + tid];
        int4   t = t4[i * 256 + tid];
        if ((unsigned)t.x < K) hist[t.x * 256 + tid] += v.x;
        if ((unsigned)t.y < K) hist[t.y * 256 + tid] += v.y;
        if ((unsigned)t.z < K) hist[t.z * 256 + tid] += v.z;
        if ((unsigned)t.w < K) hist[t.w * 256 + tid] += v.w;
    }
    __syncthreads();
    const int wid = tid >> 6, lane = tid & 63;
    for (int k = 0; k < K; ++k) {
        float v = hist[k * 256 + tid];
        for (int off = 32; off; off >>= 1) v += __shfl_xor(v, off);
        if (lane == 0) red[k][wid] = v;
    }
    __syncthreads();
    if (tid < K)
        sums[((size_t)(z * B + b) * K + tid) * C + c] =
            red[tid][0] + red[tid][1] + red[tid][2] + red[tid][3];
}

// ---------------- means + center norms ----------------
__global__ __launch_bounds__(256) void k_means(const float* __restrict__ sums,
                                               const int* __restrict__ counts,
                                               float* __restrict__ means,
                                               float* __restrict__ ny) {
    __shared__ float red0[4], red1[4];
    const int tid = threadIdx.x;
    const int bk = blockIdx.x;                      // b*K + k
    const float inv = 1.0f / ((float)counts[bk] + EPS_MEAN);
    const size_t i0 = (size_t)bk * C + tid;         // z = 0 (S)
    const size_t i1 = (size_t)(B * K + bk) * C + tid; // z = 1 (T)
    float m0 = sums[i0] * inv, m1 = sums[i1] * inv;
    means[i0] = m0; means[i1] = m1;
    float s0 = m0 * m0, s1 = m1 * m1;
    for (int off = 32; off; off >>= 1) {
        s0 += __shfl_xor(s0, off);
        s1 += __shfl_xor(s1, off);
    }
    const int wid = tid >> 6, lane = tid & 63;
    if (lane == 0) { red0[wid] = s0; red1[wid] = s1; }
    __syncthreads();
    if (tid == 0) ny[bk]         = sqrtf(red0[0] + red0[1] + red0[2] + red0[3]);
    if (tid == 1) ny[B * K + bk] = sqrtf(red1[0] + red1[1] + red1[2] + red1[3]);
}

// ---------------- per-pixel cosine sims + loss accumulation ----------------
__global__ __launch_bounds__(256) void k_loss(const float* __restrict__ fS,
                                              const float* __restrict__ fT,
                                              const int* __restrict__ target,
                                              const float* __restrict__ means,
                                              const float* __restrict__ ny,
                                              float* __restrict__ loss_acc) {
    __shared__ float mS[K * PAD];
    __shared__ float mT[K * PAD];
    __shared__ float nys[2 * K];
    __shared__ float red[4];
    const int tid = threadIdx.x;
    const int b = blockIdx.y;
    // stage per-b means tables into LDS (padded stride for bank spread)
    for (int idx = tid; idx < K * C; idx += 256) {
        int k = idx >> 8, c = idx & 255;
        mS[k * PAD + c] = means[((size_t)b * K + k) * C + c];
        mT[k * PAD + c] = means[((size_t)(B * K + b * K + k)) * C + c];
    }
    if (tid < 2 * K)
        nys[tid] = ny[(tid < K) ? (b * K + tid) : (B * K + b * K + (tid - K))];
    __syncthreads();

    const int px = blockIdx.x * 256 + tid;
    const int k = target[b * HW + px];
    const bool valid = (unsigned)k < (unsigned)K;
    const int kk = valid ? k : 0;
    const float* pS = fS + (size_t)b * C * HW + px;
    const float* pT = fT + (size_t)b * C * HW + px;
    const float* msrow = &mS[kk * PAD];
    const float* mtrow = &mT[kk * PAD];
    float dS = 0.f, qS = 0.f, dT = 0.f, qT = 0.f;
#pragma unroll 4
    for (int c = 0; c < C; ++c) {
        float vS = pS[(size_t)c * HW];
        float vT = pT[(size_t)c * HW];
        dS += vS * msrow[c]; qS += vS * vS;
        dT += vT * mtrow[c]; qT += vT * vT;
    }
    float psS = dS / fmaxf(sqrtf(qS) * nys[kk], EPS_COS);
    float psT = dT / fmaxf(sqrtf(qT) * nys[K + kk], EPS_COS);
    float d = valid ? (psS - psT) : 0.0f;   // invalid label -> both sims==1 -> 0
    float v = d * d;
    for (int off = 32; off; off >>= 1) v += __shfl_xor(v, off);
    const int wid = tid >> 6, lane = tid & 63;
    if (lane == 0) red[wid] = v;
    __syncthreads();
    if (tid == 0) atomicAdd(loss_acc, red[0] + red[1] + red[2] + red[3]);
}

__global__ void k_final(const float* __restrict__ loss_acc, float* __restrict__ out) {
    out[0] = loss_acc[0] * (1.0f / (float)(B * HW));
}

extern "C" void kernel_launch(void* const* d_in, const int* in_sizes, int n_in,
                              void* d_out, int out_size, void* d_ws, size_t ws_size,
                              hipStream_t stream) {
    const float* fS     = (const float*)d_in[0];
    const float* fT     = (const float*)d_in[1];
    const int*   target = (const int*)d_in[2];
    float* out = (float*)d_out;
    char*  ws  = (char*)d_ws;

    // ws layout (bytes): [0] loss_acc(4) | [64] sums(311296) | [+311296] means(311296)
    //                    | counts(608) | ny(1216)   — total ~625 KB
    float* loss_acc = (float*)ws;
    float* sums     = (float*)(ws + 64);
    float* means    = (float*)(ws + 64 + 311296);
    int*   counts   = (int*)  (ws + 64 + 622592);
    float* ny       = (float*)(ws + 64 + 622592 + 1024);

    hipMemsetAsync(loss_acc, 0, 4, stream);
    k_counts<<<B, 256, 0, stream>>>(target, counts);
    k_sums<<<dim3(C, B, 2), 256, 0, stream>>>(fS, fT, target, sums);
    k_means<<<B * K, 256, 0, stream>>>(sums, counts, means, ny);
    k_loss<<<dim3(HW / 256, B), 256, 0, stream>>>(fS, fT, target, means, ny, loss_acc);
    k_final<<<1, 1, 0, stream>>>(loss_acc, out);
}